// Round 1
// baseline (177.153 us; speedup 1.0000x reference)
//
#include <hip/hip_runtime.h>
#include <hip/hip_bf16.h>

// TripletLoss: N=8192 rows, D=128, 512 classes. Fused pairwise-distance +
// shift-stabilized softmax mining. dist in [0,~25] so exp(dist-30) (pos) and
// exp(-dist) (neg) never overflow/underflow fp32 -> partials are plain sums,
// mergeable across j-split blocks without online-max tracking.

typedef __bf16 bf16x8 __attribute__((ext_vector_type(8)));
typedef float f32x4 __attribute__((ext_vector_type(4)));

#define NROWS 8192
#define DIM 128
#define JSPLIT 8          // j-range splits -> 128 row-groups x 8 = 1024 blocks
#define JTILE 128         // columns staged per LDS tile
#define LDS_STRIDE 136    // 128 + 8 bf16 pad: 272B row stride -> 2-way (free) conflicts
#define MARGIN_F 0.3f
#define POS_SHIFT 30.0f

// ---------------- kernel 1: bf16 cast + row squared-norms ----------------
__global__ __launch_bounds__(64) void prep_kernel(const float* __restrict__ F,
                                                  __hip_bfloat16* __restrict__ Fb,
                                                  float* __restrict__ x2) {
    int row = blockIdx.x;
    int lane = threadIdx.x;
    const float* fr = F + (size_t)row * DIM;
    float f0 = fr[lane];
    float f1 = fr[lane + 64];
    __hip_bfloat16* fb = Fb + (size_t)row * DIM;
    fb[lane] = __float2bfloat16(f0);
    fb[lane + 64] = __float2bfloat16(f1);
    float ss = f0 * f0 + f1 * f1;
#pragma unroll
    for (int m = 32; m > 0; m >>= 1) ss += __shfl_xor(ss, m, 64);
    if (lane == 0) x2[row] = ss;
}

// ---------------- kernel 2: fused GEMM + mining epilogue ----------------
// grid (NROWS/64, JSPLIT); block 256 = 4 waves; wave w owns rows rbase..rbase+15.
__global__ __launch_bounds__(256, 4) void pairs_kernel(
        const __hip_bfloat16* __restrict__ Fb,
        const float* __restrict__ x2,
        const int* __restrict__ labels,
        float4* __restrict__ partial) {
    __shared__ __hip_bfloat16 sB[JTILE * LDS_STRIDE];
    __shared__ int sLab[JTILE];
    __shared__ float sX2[JTILE];

    const int tid = threadIdx.x;
    const int wave = tid >> 6;
    const int lane = tid & 63;
    const int quad = lane >> 4;   // lane/16
    const int lm = lane & 15;

    const int rbase = blockIdx.x * 64 + wave * 16;

    // A fragments (16 rows x K=128) held in registers for the whole j loop.
    // A layout (mfma_f32_16x16x32_bf16): A[m=lane&15][k = quad*8 + j]
    bf16x8 a[4];
#pragma unroll
    for (int kc = 0; kc < 4; ++kc)
        a[kc] = *(const bf16x8*)(Fb + (size_t)(rbase + lm) * DIM + kc * 32 + quad * 8);

    // C/D layout: col = lane&15, row = quad*4 + reg  (m89/m91-verified)
    int ig[4]; float x2i[4]; int labi[4];
#pragma unroll
    for (int r = 0; r < 4; ++r) {
        ig[r] = rbase + quad * 4 + r;
        x2i[r] = x2[ig[r]];
        labi[r] = labels[ig[r]];
    }

    float posl[4] = {0.f, 0.f, 0.f, 0.f}, poss[4] = {0.f, 0.f, 0.f, 0.f};
    float negl[4] = {0.f, 0.f, 0.f, 0.f}, negs[4] = {0.f, 0.f, 0.f, 0.f};

    const int j0 = blockIdx.y * (NROWS / JSPLIT);
    const int jiters = (NROWS / JSPLIT) / JTILE;   // 8

    for (int jb = 0; jb < jiters; ++jb) {
        const int jbase = j0 + jb * JTILE;
        __syncthreads();   // protect LDS from previous iter's readers
        // stage 128 rows x 256B, 16B per thread-chunk, coalesced
#pragma unroll
        for (int s = 0; s < 8; ++s) {
            int c = tid + s * 256;       // 0..2047
            int jr = c >> 4;             // staged row
            int ck = c & 15;             // 16B chunk in row
            bf16x8 v = *(const bf16x8*)(Fb + (size_t)(jbase + jr) * DIM + ck * 8);
            *(bf16x8*)(sB + jr * LDS_STRIDE + ck * 8) = v;
        }
        if (tid < JTILE) {
            sLab[tid] = labels[jbase + tid];
            sX2[tid] = x2[jbase + tid];
        }
        __syncthreads();

#pragma unroll
        for (int jt = 0; jt < 8; ++jt) {
            const int jl = jt * 16 + lm;
            // B layout: B[k = quad*8 + j][n = lane&15]; B = F_J^T so lane
            // reads F[jbase+jl][k] -- same fragment shape as A.
            const __hip_bfloat16* bp = sB + jl * LDS_STRIDE + quad * 8;
            f32x4 acc = {0.f, 0.f, 0.f, 0.f};
#pragma unroll
            for (int kc = 0; kc < 4; ++kc) {
                bf16x8 b = *(const bf16x8*)(bp + kc * 32);
                acc = __builtin_amdgcn_mfma_f32_16x16x32_bf16(a[kc], b, acc, 0, 0, 0);
            }
            const int labj = sLab[jl];
            const float x2j = sX2[jl];
            const int jglob = jbase + jl;
#pragma unroll
            for (int r = 0; r < 4; ++r) {
                float d2 = x2i[r] + x2j - 2.0f * acc[r];
                d2 = fmaxf(d2, 1e-8f);
                float dist = sqrtf(d2);
                bool same = (labj == labi[r]);
                float ne = __expf(-dist);
                if (!same) {
                    negl[r] += ne;
                    negs[r] += ne * dist;
                }
                if (same && (jglob != ig[r])) {   // rare (~0.2%): branch skips exp
                    float pe = __expf(dist - POS_SHIFT);
                    posl[r] += pe;
                    poss[r] += pe * dist;
                }
            }
        }
    }

    // reduce across the 16 lanes of each quad (they share the same C rows)
#pragma unroll
    for (int m = 1; m < 16; m <<= 1) {
#pragma unroll
        for (int r = 0; r < 4; ++r) {
            posl[r] += __shfl_xor(posl[r], m, 64);
            poss[r] += __shfl_xor(poss[r], m, 64);
            negl[r] += __shfl_xor(negl[r], m, 64);
            negs[r] += __shfl_xor(negs[r], m, 64);
        }
    }
    if (lm == 0) {
#pragma unroll
        for (int r = 0; r < 4; ++r)
            partial[(size_t)blockIdx.y * NROWS + ig[r]] =
                make_float4(posl[r], poss[r], negl[r], negs[r]);
    }
}

// ---------------- kernel 3: per-row loss + scalar reduction ----------------
__global__ __launch_bounds__(256) void finalize_kernel(const float4* __restrict__ partial,
                                                       float* __restrict__ out) {
    __shared__ float sSum[256];
    __shared__ float sCnt[256];
    const int t = threadIdx.x;
    float sum = 0.f, cnt = 0.f;
    for (int row = t; row < NROWS; row += 256) {
        float pl = 0.f, ps = 0.f, nl = 0.f, ns = 0.f;
        for (int s = 0; s < JSPLIT; ++s) {
            float4 p = partial[(size_t)s * NROWS + row];
            pl += p.x; ps += p.y; nl += p.z; ns += p.w;
        }
        if (pl > 0.f && nl > 0.f) {           // valid: has >=1 pos and >=1 neg
            float wp = ps / pl;
            float wn = ns / nl;
            float x = wp - wn + MARGIN_F;
            // stable softplus
            float loss = fmaxf(x, 0.f) + log1pf(__expf(-fabsf(x)));
            sum += loss;
            cnt += 1.f;
        }
    }
    sSum[t] = sum; sCnt[t] = cnt;
    __syncthreads();
    for (int s = 128; s > 0; s >>= 1) {
        if (t < s) { sSum[t] += sSum[t + s]; sCnt[t] += sCnt[t + s]; }
        __syncthreads();
    }
    if (t == 0) out[0] = sSum[0] / fmaxf(sCnt[0], 1.0f);
}

extern "C" void kernel_launch(void* const* d_in, const int* in_sizes, int n_in,
                              void* d_out, int out_size, void* d_ws, size_t ws_size,
                              hipStream_t stream) {
    const float* F = (const float*)d_in[0];     // [8192,128] fp32
    const int* labels = (const int*)d_in[1];    // [8192] int32
    float* out = (float*)d_out;                 // scalar fp32

    char* ws = (char*)d_ws;
    __hip_bfloat16* Fb = (__hip_bfloat16*)ws;                          // 2 MB
    float* x2 = (float*)(ws + (size_t)NROWS * DIM * 2);                // 32 KB
    float4* partial = (float4*)(ws + (size_t)NROWS * DIM * 2 + NROWS * 4);  // 512 KB

    prep_kernel<<<NROWS, 64, 0, stream>>>(F, Fb, x2);
    dim3 grid(NROWS / 64, JSPLIT);
    pairs_kernel<<<grid, 256, 0, stream>>>(Fb, x2, labels, partial);
    finalize_kernel<<<1, 256, 0, stream>>>(partial, out);
}